// Round 6
// baseline (743.449 us; speedup 1.0000x reference)
//
#include <hip/hip_runtime.h>
#include <hip/hip_bf16.h>
#include <math.h>

#define HID 128

typedef __attribute__((ext_vector_type(8))) short short8;
typedef __attribute__((ext_vector_type(4))) short short4v;
typedef __attribute__((ext_vector_type(4))) float f32x4;
typedef __attribute__((ext_vector_type(2))) float f32x2;
typedef __attribute__((ext_vector_type(4))) int int4v;
typedef __attribute__((ext_vector_type(2))) unsigned int uint2v;
typedef __attribute__((ext_vector_type(4))) unsigned short ushort4v;
typedef __attribute__((ext_vector_type(2))) unsigned short ushort2v;
typedef __attribute__((ext_vector_type(2))) _Float16 half2v;

static inline size_t align256(size_t x){ return (x + 255) & ~(size_t)255; }

__device__ inline unsigned short f2bf(float f) {
  union { float f; unsigned u; } uf; uf.f = f;
  unsigned r = uf.u + 0x7fff + ((uf.u >> 16) & 1);  // RNE
  return (unsigned short)(r >> 16);
}
__device__ inline unsigned short f2h(float f) {
  union { _Float16 h; unsigned short u; } c; c.h = (_Float16)f; return c.u;
}
__device__ inline half2v b2h2(unsigned u) {
  union { unsigned u; half2v h; } c; c.u = u; return c.h;
}

// sum across each 16-lane group (DPP row) — pure VALU, no LDS pipe
__device__ inline float dpp_rsum16(float x) {
  int v;
  v = __builtin_amdgcn_update_dpp(0, __float_as_int(x), 0xB1, 0xF, 0xF, true);  // quad_perm [1,0,3,2]
  x += __int_as_float(v);
  v = __builtin_amdgcn_update_dpp(0, __float_as_int(x), 0x4E, 0xF, 0xF, true);  // quad_perm [2,3,0,1]
  x += __int_as_float(v);
  v = __builtin_amdgcn_update_dpp(0, __float_as_int(x), 0x124, 0xF, 0xF, true); // row_ror:4
  x += __int_as_float(v);
  v = __builtin_amdgcn_update_dpp(0, __float_as_int(x), 0x128, 0xF, 0xF, true); // row_ror:8
  x += __int_as_float(v);
  return x;
}

// ---- fused: weight prep (blocks 0-127) || chunked LDS histogram (blocks 128+) ----
// hist: block owns 512 dst bins, scans half the edge list; LDS atomics only.
__global__ __launch_bounds__(512) void k_prep(
    const float* W0, const float* W1, const float* W2, const float* W3,
    const float* W4, const float* W5, const float* W6, const float* W7,
    const float* b0, const float* b1, const float* b2, const float* b3,
    const float* b4, const float* b5, const float* b6, const float* b7,
    unsigned short* Wcat, float* Bcat,
    const int* __restrict__ edst, int* __restrict__ degA, int* __restrict__ degB, int e)
{
  __shared__ float tl[32][33];
  __shared__ int hh[512];
  int t = threadIdx.x;
  if (blockIdx.x >= 128) {
    int hb = blockIdx.x - 128;
    int chunk = hb >> 1, half = hb & 1;
    int lo = chunk << 9;
    hh[t] = 0;
    __syncthreads();
    int eh = e >> 1;
    int i0 = half ? eh : 0, i1 = half ? e : eh;
    for (int i = i0 + t; i < i1; i += 512) {
      unsigned u = (unsigned)(edst[i] - lo);
      if (u < 512u) atomicAdd(&hh[u], 1);
    }
    __syncthreads();
    (half ? degB : degA)[lo + t] = hh[t];
    return;
  }
  const float* Ws[8] = {W0, W1, W2, W3, W4, W5, W6, W7};
  const float* bs[8] = {b0, b1, b2, b3, b4, b5, b6, b7};
  int m = blockIdx.x >> 4, tile = blockIdx.x & 15;
  int tr = (tile >> 2) * 32, tc = (tile & 3) * 32;
  int tx = t & 31, ty = t >> 5;   // 32 x 16
  const float* Wm = Ws[m];
  #pragma unroll
  for (int r = 0; r < 32; r += 16) tl[ty + r][tx] = Wm[(tr + ty + r) * 128 + tc + tx];
  __syncthreads();
  #pragma unroll
  for (int r = 0; r < 32; r += 16)
    Wcat[m * 16384 + (tc + ty + r) * 128 + tr + tx] = f2bf(tl[tx][ty + r]);
  if (tile == 0 && t < 128) Bcat[m * 128 + t] = bs[m][t];
}

// ---------------- CSR scan ----------------
__global__ void k_scan_a(const int* __restrict__ degA, const int* __restrict__ degB,
                         int* __restrict__ rowptr, int* __restrict__ bsum, int n) {
  __shared__ int tmp[512];
  int t = threadIdx.x, i = blockIdx.x * 512 + t;
  int v = (i < n) ? degA[i] + degB[i] : 0;
  tmp[t] = v;
  __syncthreads();
  for (int off = 1; off < 512; off <<= 1) {
    int u = (t >= off) ? tmp[t - off] : 0;
    __syncthreads();
    tmp[t] += u;
    __syncthreads();
  }
  if (i < n) rowptr[i] = tmp[t] - v;
  if (t == 511) bsum[blockIdx.x] = tmp[t];
}

// each block re-reduces bsum[0..bid) itself, then applies
__global__ void k_scan_c(int* __restrict__ rowptr, const int* __restrict__ bsum,
                         int n, int e, int nb) {
  __shared__ int sred[8];
  __shared__ int base_sh;
  int t = threadIdx.x;
  int v = (t < nb && t < (int)blockIdx.x) ? bsum[t] : 0;
  #pragma unroll
  for (int off = 32; off >= 1; off >>= 1) v += __shfl_xor(v, off);
  if ((t & 63) == 0) sred[t >> 6] = v;
  __syncthreads();
  if (t == 0) {
    int b = 0;
    #pragma unroll
    for (int j = 0; j < 8; ++j) b += sred[j];
    base_sh = b;
  }
  __syncthreads();
  int i = blockIdx.x * 512 + t;
  if (i < n) rowptr[i] += base_sh;
  if (i == 0) rowptr[n] = e;
}

// ---- chunked scatter: block owns 512 dst bins, LDS cursors, zero global atomics ----
__global__ __launch_bounds__(512) void k_scatter(
    const int* __restrict__ esrc, const int* __restrict__ edst,
    const int* __restrict__ rowptr, const int* __restrict__ degA,
    int* __restrict__ csrc, int e, int n)
{
  __shared__ int cur[512];
  int t = threadIdx.x;
  int chunk = blockIdx.x >> 1, half = blockIdx.x & 1;
  int lo = chunk << 9;
  int idx = lo + t;
  int base = 0;
  if (idx < n) {
    base = rowptr[idx];
    if (half) base += degA[idx];
  }
  cur[t] = base;
  __syncthreads();
  int eh = e >> 1;
  int i0 = half ? eh : 0, i1 = half ? e : eh;
  for (int i = i0 + t; i < i1; i += 512) {
    unsigned u = (unsigned)(edst[i] - lo);
    if (u < 512u) {
      int pos = atomicAdd(&cur[u], 1);
      csrc[pos] = esrc[i] << 9;   // byte offset into KVb
    }
  }
}

// ---------------- fused QKVS projection GEMM (bf16 MFMA, 64-row tile, 4 phases) --------
// outputs: Q (f16, pre-scaled by log2e/sqrt(32)), KV interleaved (f16), S (f16)
template<int ABF16>
__global__ __launch_bounds__(256, 3) void k_qkvs(
    const void* __restrict__ Ain, const unsigned short* __restrict__ Wl,
    const float* __restrict__ Bl, unsigned short* __restrict__ Qb,
    unsigned short* __restrict__ KVb, unsigned short* __restrict__ Sb, int n)
{
  __shared__ unsigned short sA[64 * 128];    // 16 KB
  __shared__ unsigned short sW[128 * 128];   // 32 KB
  const int tid = threadIdx.x;
  const int rb = blockIdx.x * 64;
  const float QSC = 0.25503487f;   // (1/sqrt(32)) * log2(e)

  if (ABF16) {
    const unsigned short* A = (const unsigned short*)Ain;
    #pragma unroll
    for (int it = 0; it < 4; ++it) {
      int q = tid + it * 256;
      int row = q >> 4, ch = q & 15;
      int gr = rb + row;
      short8 h = {0,0,0,0,0,0,0,0};
      if (gr < n) h = *reinterpret_cast<const short8*>(A + (size_t)gr * HID + ch * 8);
      *reinterpret_cast<short8*>(&sA[row * 128 + ((ch ^ (row & 7)) << 3)]) = h;
    }
  } else {
    const float* A = (const float*)Ain;
    #pragma unroll
    for (int it = 0; it < 8; ++it) {
      int q = tid + it * 256;
      int row = q >> 5, c4 = (q & 31) * 4;
      int gr = rb + row;
      f32x4 a = {0.f, 0.f, 0.f, 0.f};
      if (gr < n) a = *reinterpret_cast<const f32x4*>(A + (size_t)gr * HID + c4);
      short4v h;
      h.x = (short)f2bf(a.x); h.y = (short)f2bf(a.y);
      h.z = (short)f2bf(a.z); h.w = (short)f2bf(a.w);
      int eloff = row * 128 + (((c4 >> 3) ^ (row & 7)) << 3) + (c4 & 7);
      *reinterpret_cast<short4v*>(&sA[eloff]) = h;
    }
  }

  const int lane = tid & 63;
  const int wv = tid >> 6;

  auto stageW = [&](int y) {
    const unsigned short* Wy = Wl + (size_t)y * 16384;
    #pragma unroll
    for (int it = 0; it < 8; ++it) {
      int q = tid + it * 256;
      int c = q >> 4, ch = q & 15;
      short8 w = *reinterpret_cast<const short8*>(Wy + c * 128 + ch * 8);
      *reinterpret_cast<short8*>(&sW[c * 128 + ((ch ^ (c & 7)) << 3)]) = w;
    }
  };

  stageW(0);
  __syncthreads();

  short8 af[4];
  #pragma unroll
  for (int ks = 0; ks < 4; ++ks) {
    int ch = ks * 4 + (lane >> 4);
    int row = wv * 16 + (lane & 15);
    af[ks] = *reinterpret_cast<const short8*>(&sA[row * 128 + ((ch ^ (row & 7)) << 3)]);
  }

  f32x4 acc[8];
  auto compute = [&]() {
    #pragma unroll
    for (int mf = 0; mf < 8; ++mf) acc[mf] = (f32x4){0.f, 0.f, 0.f, 0.f};
    #pragma unroll
    for (int ks = 0; ks < 4; ++ks) {
      int ch = ks * 4 + (lane >> 4);
      short8 wf[8];
      #pragma unroll
      for (int mf = 0; mf < 8; ++mf) {
        int wc = mf * 16 + (lane & 15);
        wf[mf] = *reinterpret_cast<const short8*>(&sW[wc * 128 + ((ch ^ (wc & 7)) << 3)]);
      }
      #pragma unroll
      for (int mf = 0; mf < 8; ++mf)
        acc[mf] = __builtin_amdgcn_mfma_f32_16x16x32_bf16(wf[mf], af[ks], acc[mf], 0, 0, 0);
    }
  };

  const int gr = rb + wv * 16 + (lane & 15);
  const int cbase = (lane >> 4) << 2;

  // ---- phase 0: Q (f16, pre-scaled) ----
  compute();
  if (gr < n) {
    #pragma unroll
    for (int mf = 0; mf < 8; ++mf) {
      int c0 = mf * 16 + cbase;
      f32x4 b = *reinterpret_cast<const f32x4*>(Bl + 0 * 128 + c0);
      f32x4 v = acc[mf];
      ushort4v h;
      h.x = f2h((v.x + b.x) * QSC); h.y = f2h((v.y + b.y) * QSC);
      h.z = f2h((v.z + b.z) * QSC); h.w = f2h((v.w + b.w) * QSC);
      *reinterpret_cast<ushort4v*>(Qb + (size_t)gr * HID + c0) = h;
    }
  }

  // ---- phase 1: S (f16) ----
  __syncthreads();
  stageW(3);
  __syncthreads();
  compute();
  if (gr < n) {
    #pragma unroll
    for (int mf = 0; mf < 8; ++mf) {
      int c0 = mf * 16 + cbase;
      f32x4 b = *reinterpret_cast<const f32x4*>(Bl + 3 * 128 + c0);
      f32x4 v = acc[mf];
      ushort4v h;
      h.x = f2h(v.x + b.x); h.y = f2h(v.y + b.y);
      h.z = f2h(v.z + b.z); h.w = f2h(v.w + b.w);
      *reinterpret_cast<ushort4v*>(Sb + (size_t)gr * HID + c0) = h;
    }
  }

  // ---- phase 2: K (held in registers) ----
  __syncthreads();
  stageW(1);
  __syncthreads();
  compute();
  f32x4 kacc[8];
  #pragma unroll
  for (int mf = 0; mf < 8; ++mf) kacc[mf] = acc[mf];

  // ---- phase 3: V, store interleaved KV (f16) ----
  __syncthreads();
  stageW(2);
  __syncthreads();
  compute();
  if (gr < n) {
    #pragma unroll
    for (int mf = 0; mf < 8; ++mf) {
      int c0 = mf * 16 + cbase;
      f32x4 bk = *reinterpret_cast<const f32x4*>(Bl + 1 * 128 + c0);
      f32x4 bv = *reinterpret_cast<const f32x4*>(Bl + 2 * 128 + c0);
      f32x4 kv = kacc[mf], vv = acc[mf];
      short8 h;
      h[0] = (short)f2h(kv.x + bk.x); h[1] = (short)f2h(kv.y + bk.y);
      h[2] = (short)f2h(vv.x + bv.x); h[3] = (short)f2h(vv.y + bv.y);
      h[4] = (short)f2h(kv.z + bk.z); h[5] = (short)f2h(kv.w + bk.w);
      h[6] = (short)f2h(vv.z + bv.z); h[7] = (short)f2h(vv.w + bv.w);
      *reinterpret_cast<short8*>(KVb + (size_t)gr * 256 + 2 * c0) = h;
    }
  }
}

// ---------------- fused attention + skip + relu (f16, v_dot2, deferred rescale) --------
__global__ __launch_bounds__(256, 8) void k_attn2(
    const unsigned short* __restrict__ Qb, const unsigned short* __restrict__ KVb,
    const unsigned short* __restrict__ Sb, const int* __restrict__ rowptr,
    const int* __restrict__ csrc, unsigned short* __restrict__ Hout, int n)
{
  int wid = blockIdx.x * 4 + (threadIdx.x >> 6);
  if (wid >= n) return;
  int lane = threadIdx.x & 63;
  half2v qh = b2h2(*reinterpret_cast<const unsigned*>(Qb + (size_t)wid * HID + 2 * lane));
  int e0 = rowptr[wid], deg = rowptr[wid + 1] - e0;
  const int* cp = csrc + e0;
  const char* kvb = (const char*)KVb + lane * 8;
  float m = -INFINITY, s = 0.f, a0 = 0.f, a1 = 0.f;

  auto LDo = [&](int off) -> uint2v {
    return *reinterpret_cast<const uint2v*>(kvb + (unsigned)off);
  };
  auto proc1 = [&](uint2v kv) {
    float lg = dpp_rsum16(__builtin_amdgcn_fdot2(qh, b2h2(kv.x), 0.f, false));
    if (!__all(lg <= m + 11.5f)) {
      float nm = fmaxf(m, lg);
      float cc = __builtin_amdgcn_exp2f(m - nm);
      s *= cc; a0 *= cc; a1 *= cc; m = nm;
    }
    float p = __builtin_amdgcn_exp2f(lg - m);
    half2v vh = b2h2(kv.y);
    s += p;
    a0 = fmaf(p, (float)vh.x, a0);
    a1 = fmaf(p, (float)vh.y, a1);
  };
  auto proc4 = [&](uint2v e0v, uint2v e1v, uint2v e2v, uint2v e3v) {
    float l0 = dpp_rsum16(__builtin_amdgcn_fdot2(qh, b2h2(e0v.x), 0.f, false));
    float l1 = dpp_rsum16(__builtin_amdgcn_fdot2(qh, b2h2(e1v.x), 0.f, false));
    float l2 = dpp_rsum16(__builtin_amdgcn_fdot2(qh, b2h2(e2v.x), 0.f, false));
    float l3 = dpp_rsum16(__builtin_amdgcn_fdot2(qh, b2h2(e3v.x), 0.f, false));
    float qm = fmaxf(fmaxf(l0, l1), fmaxf(l2, l3));
    if (!__all(qm <= m + 11.5f)) {       // rare, wave-uniform
      float nm = fmaxf(m, qm);
      float cc = __builtin_amdgcn_exp2f(m - nm);
      s *= cc; a0 *= cc; a1 *= cc; m = nm;
    }
    float p0 = __builtin_amdgcn_exp2f(l0 - m);
    float p1 = __builtin_amdgcn_exp2f(l1 - m);
    float p2 = __builtin_amdgcn_exp2f(l2 - m);
    float p3 = __builtin_amdgcn_exp2f(l3 - m);
    s += (p0 + p1) + (p2 + p3);
    half2v v0 = b2h2(e0v.y), v1 = b2h2(e1v.y), v2 = b2h2(e2v.y), v3 = b2h2(e3v.y);
    a0 = fmaf(p3, (float)v3.x, fmaf(p2, (float)v2.x, fmaf(p1, (float)v1.x, fmaf(p0, (float)v0.x, a0))));
    a1 = fmaf(p3, (float)v3.y, fmaf(p2, (float)v2.y, fmaf(p1, (float)v1.y, fmaf(p0, (float)v0.y, a1))));
  };

  int nq = deg >> 2, r = deg & 3;
  if (nq) {
    int4v o; __builtin_memcpy(&o, cp, 16);
    uint2v b0 = LDo(o.x), b1 = LDo(o.y), b2 = LDo(o.z), b3 = LDo(o.w);
    for (int q = 1; q < nq; ++q) {
      int4v no; __builtin_memcpy(&no, cp + 4 * q, 16);
      uint2v n0 = LDo(no.x), n1 = LDo(no.y), n2 = LDo(no.z), n3 = LDo(no.w);
      proc4(b0, b1, b2, b3);
      b0 = n0; b1 = n1; b2 = n2; b3 = n3;
    }
    proc4(b0, b1, b2, b3);
  }
  int tb = nq * 4;
  for (int i = 0; i < r; ++i) proc1(LDo(cp[tb + i]));

  float inv = (s > 0.f) ? 1.f / s : 0.f;
  half2v sh = b2h2(*reinterpret_cast<const unsigned*>(Sb + (size_t)wid * HID + 2 * lane));
  ushort2v h;
  h.x = f2bf(fmaxf(fmaf(a0, inv, (float)sh.x), 0.f));
  h.y = f2bf(fmaxf(fmaf(a1, inv, (float)sh.y), 0.f));
  *reinterpret_cast<ushort2v*>(Hout + (size_t)wid * HID + 2 * lane) = h;
}

// ---------------- fused mean-pool + FC (64 blocks, one per group; zero atomics) --------
__device__ inline float bf2f(unsigned short h) {
  union { unsigned u; float f; } uf; uf.u = ((unsigned)h) << 16; return uf.f;
}
__global__ __launch_bounds__(256) void k_poolfc(
    const unsigned short* __restrict__ H, const int* __restrict__ batch,
    const float* __restrict__ Wfc, const float* __restrict__ bfc,
    float* __restrict__ out, int n)
{
  int g = blockIdx.x;
  int lo = 0, hi = n;
  while (lo < hi) { int mid = (lo + hi) >> 1; if (batch[mid] < g) lo = mid + 1; else hi = mid; }
  int start = lo;
  hi = n;
  while (lo < hi) { int mid = (lo + hi) >> 1; if (batch[mid] < g + 1) lo = mid + 1; else hi = mid; }
  int end = lo;

  int t = threadIdx.x;
  int col = t & 127, rr = t >> 7;        // 2 row-streams x 128 cols
  float a0 = 0.f, a1 = 0.f, a2 = 0.f, a3 = 0.f;
  int i = start + rr;
  for (; i + 6 < end; i += 8) {
    a0 += bf2f(H[(size_t)i * HID + col]);
    a1 += bf2f(H[(size_t)(i + 2) * HID + col]);
    a2 += bf2f(H[(size_t)(i + 4) * HID + col]);
    a3 += bf2f(H[(size_t)(i + 6) * HID + col]);
  }
  for (; i < end; i += 2) a0 += bf2f(H[(size_t)i * HID + col]);
  float v = ((a0 + a1) + (a2 + a3)) * Wfc[col];

  __shared__ float red[4];
  #pragma unroll
  for (int off = 32; off >= 1; off >>= 1) v += __shfl_xor(v, off);
  if ((t & 63) == 0) red[t >> 6] = v;
  __syncthreads();
  if (t == 0) {
    float tot = (red[0] + red[1]) + (red[2] + red[3]);
    float cnt = (float)(end - start);
    out[g] = tot / fmaxf(cnt, 1.f) + bfc[0];
  }
}

extern "C" void kernel_launch(void* const* d_in, const int* in_sizes, int n_in,
                              void* d_out, int out_size, void* d_ws, size_t ws_size,
                              hipStream_t stream)
{
  const float* x   = (const float*)d_in[0];
  const int*   ei  = (const int*)d_in[1];
  const int*   bat = (const int*)d_in[2];
  const float *Wq1 = (const float*)d_in[3],  *bq1 = (const float*)d_in[4];
  const float *Wk1 = (const float*)d_in[5],  *bk1 = (const float*)d_in[6];
  const float *Wv1 = (const float*)d_in[7],  *bv1 = (const float*)d_in[8];
  const float *Ws1 = (const float*)d_in[9],  *bs1 = (const float*)d_in[10];
  const float *Wq2 = (const float*)d_in[11], *bq2 = (const float*)d_in[12];
  const float *Wk2 = (const float*)d_in[13], *bk2 = (const float*)d_in[14];
  const float *Wv2 = (const float*)d_in[15], *bv2 = (const float*)d_in[16];
  const float *Ws2 = (const float*)d_in[17], *bs2 = (const float*)d_in[18];
  const float *Wfc = (const float*)d_in[19], *bfc = (const float*)d_in[20];
  float* out = (float*)d_out;

  const int N = in_sizes[0] / HID;
  const int E = in_sizes[1] / 2;
  const int G = 64;
  const int NCH = (N + 511) >> 9;            // 512-dst chunks

  char* p = (char*)d_ws;
  auto alloc = [&](size_t bytes) -> char* { char* r = p; p += align256(bytes); return r; };
  unsigned short* Qb  = (unsigned short*)alloc((size_t)N * HID * 2);   // f16
  unsigned short* KVb = (unsigned short*)alloc((size_t)N * 256 * 2);   // f16 interleaved
  unsigned short* Sb  = (unsigned short*)alloc((size_t)N * HID * 2);   // f16
  unsigned short* Hb  = (unsigned short*)alloc((size_t)N * HID * 2);   // bf16
  unsigned short* H2b = (unsigned short*)alloc((size_t)N * HID * 2);   // bf16
  unsigned short* Wcat = (unsigned short*)alloc((size_t)8 * 128 * 128 * 2);
  float* Bcat = (float*)alloc((size_t)8 * 128 * 4);
  int* rowptr = (int*)alloc((size_t)(N + 1) * sizeof(int));
  int* degA   = (int*)alloc((size_t)NCH * 512 * sizeof(int));
  int* degB   = (int*)alloc((size_t)NCH * 512 * sizeof(int));
  int* bsum   = (int*)alloc(4096);
  int* csrc   = (int*)alloc((size_t)E * sizeof(int));

  const int* esrc = ei;
  const int* edst = ei + E;

  // wprep (128 blocks) || chunked hist (2*NCH blocks); no memset, no global atomics
  k_prep<<<128 + 2 * NCH, 512, 0, stream>>>(
      Wq1, Wk1, Wv1, Ws1, Wq2, Wk2, Wv2, Ws2,
      bq1, bk1, bv1, bs1, bq2, bk2, bv2, bs2,
      Wcat, Bcat, edst, degA, degB, E);

  int SB = (N + 511) / 512;
  k_scan_a<<<SB, 512, 0, stream>>>(degA, degB, rowptr, bsum, N);
  k_scan_c<<<SB, 512, 0, stream>>>(rowptr, bsum, N, E, SB);
  k_scatter<<<2 * NCH, 512, 0, stream>>>(esrc, edst, rowptr, degA, csrc, E, N);

  int QB = (N + 63) / 64;
  // layer 1 (fp32 input)
  k_qkvs<0><<<QB, 256, 0, stream>>>(x, Wcat, Bcat, Qb, KVb, Sb, N);
  k_attn2<<<(N + 3) / 4, 256, 0, stream>>>(Qb, KVb, Sb, rowptr, csrc, Hb, N);
  // layer 2 (bf16 input)
  k_qkvs<1><<<QB, 256, 0, stream>>>(Hb, Wcat + 4 * 16384, Bcat + 512, Qb, KVb, Sb, N);
  k_attn2<<<(N + 3) / 4, 256, 0, stream>>>(Qb, KVb, Sb, rowptr, csrc, H2b, N);
  // mean-pool + fc
  k_poolfc<<<G, 256, 0, stream>>>(H2b, bat, Wfc, bfc, out, N);
}

// Round 7
// 365.859 us; speedup vs baseline: 2.0321x; 2.0321x over previous
//
#include <hip/hip_runtime.h>
#include <hip/hip_bf16.h>
#include <math.h>

#define HID 128

typedef __attribute__((ext_vector_type(8))) short short8;
typedef __attribute__((ext_vector_type(4))) short short4v;
typedef __attribute__((ext_vector_type(4))) float f32x4;
typedef __attribute__((ext_vector_type(4))) int int4v;
typedef __attribute__((ext_vector_type(2))) unsigned int uint2v;
typedef __attribute__((ext_vector_type(4))) unsigned short ushort4v;
typedef __attribute__((ext_vector_type(2))) unsigned short ushort2v;
typedef __attribute__((ext_vector_type(2))) _Float16 half2v;

static inline size_t align256(size_t x){ return (x + 255) & ~(size_t)255; }

__device__ inline float bf2f(unsigned short h) {
  union { unsigned u; float f; } uf; uf.u = ((unsigned)h) << 16; return uf.f;
}
__device__ inline unsigned short f2bf(float f) {
  union { float f; unsigned u; } uf; uf.f = f;
  unsigned r = uf.u + 0x7fff + ((uf.u >> 16) & 1);  // RNE
  return (unsigned short)(r >> 16);
}
__device__ inline unsigned short f2h(float f) {
  union { _Float16 h; unsigned short u; } c; c.h = (_Float16)f; return c.u;
}
__device__ inline half2v b2h2(unsigned u) {
  union { unsigned u; half2v h; } c; c.u = u; return c.h;
}

// sum across each 16-lane group (DPP row) — pure VALU, no LDS pipe
__device__ inline float dpp_rsum16(float x) {
  int v;
  v = __builtin_amdgcn_update_dpp(0, __float_as_int(x), 0xB1, 0xF, 0xF, true);  // quad_perm [1,0,3,2]
  x += __int_as_float(v);
  v = __builtin_amdgcn_update_dpp(0, __float_as_int(x), 0x4E, 0xF, 0xF, true);  // quad_perm [2,3,0,1]
  x += __int_as_float(v);
  v = __builtin_amdgcn_update_dpp(0, __float_as_int(x), 0x124, 0xF, 0xF, true); // row_ror:4
  x += __int_as_float(v);
  v = __builtin_amdgcn_update_dpp(0, __float_as_int(x), 0x128, 0xF, 0xF, true); // row_ror:8
  x += __int_as_float(v);
  return x;
}

// ---- fused: weight prep (blocks 0-127) || hist+rank (blocks 128+) ----
// hist: rank[i] = arrival order among edges sharing dst — the atomic does double duty.
__global__ __launch_bounds__(512) void k_prep(
    const float* W0, const float* W1, const float* W2, const float* W3,
    const float* W4, const float* W5, const float* W6, const float* W7,
    const float* b0, const float* b1, const float* b2, const float* b3,
    const float* b4, const float* b5, const float* b6, const float* b7,
    unsigned short* Wcat, float* Bcat,
    const int* __restrict__ edst, int* __restrict__ deg, int* __restrict__ rank, int e)
{
  __shared__ float tl[32][33];
  int t = threadIdx.x;
  if (blockIdx.x >= 128) {
    for (int i = (blockIdx.x - 128) * 512 + t; i < e; i += 512 * 512)
      rank[i] = atomicAdd(&deg[edst[i]], 1);
    return;
  }
  const float* Ws[8] = {W0, W1, W2, W3, W4, W5, W6, W7};
  const float* bs[8] = {b0, b1, b2, b3, b4, b5, b6, b7};
  int m = blockIdx.x >> 4, tile = blockIdx.x & 15;
  int tr = (tile >> 2) * 32, tc = (tile & 3) * 32;
  int tx = t & 31, ty = t >> 5;   // 32 x 16
  const float* Wm = Ws[m];
  #pragma unroll
  for (int r = 0; r < 32; r += 16) tl[ty + r][tx] = Wm[(tr + ty + r) * 128 + tc + tx];
  __syncthreads();
  #pragma unroll
  for (int r = 0; r < 32; r += 16)
    Wcat[m * 16384 + (tc + ty + r) * 128 + tr + tx] = f2bf(tl[tx][ty + r]);
  if (tile == 0 && t < 128) Bcat[m * 128 + t] = bs[m][t];
}

// ---------------- CSR scan ----------------
__global__ void k_scan_a(const int* __restrict__ deg, int* __restrict__ rowptr,
                         int* __restrict__ bsum, int n) {
  __shared__ int tmp[512];
  int t = threadIdx.x, i = blockIdx.x * 512 + t;
  int v = (i < n) ? deg[i] : 0;
  tmp[t] = v;
  __syncthreads();
  for (int off = 1; off < 512; off <<= 1) {
    int u = (t >= off) ? tmp[t - off] : 0;
    __syncthreads();
    tmp[t] += u;
    __syncthreads();
  }
  if (i < n) rowptr[i] = tmp[t] - v;
  if (t == 511) bsum[blockIdx.x] = tmp[t];
}

// each block re-reduces bsum[0..bid) itself, then applies
__global__ void k_scan_c(int* __restrict__ rowptr, const int* __restrict__ bsum,
                         int n, int e, int nb) {
  __shared__ int sred[8];
  __shared__ int base_sh;
  int t = threadIdx.x;
  int v = (t < nb && t < (int)blockIdx.x) ? bsum[t] : 0;
  #pragma unroll
  for (int off = 32; off >= 1; off >>= 1) v += __shfl_xor(v, off);
  if ((t & 63) == 0) sred[t >> 6] = v;
  __syncthreads();
  if (t == 0) {
    int b = 0;
    #pragma unroll
    for (int j = 0; j < 8; ++j) b += sred[j];
    base_sh = b;
  }
  __syncthreads();
  int i = blockIdx.x * 512 + t;
  if (i < n) rowptr[i] += base_sh;
  if (i == 0) rowptr[n] = e;
}

// ---- atomic-free scatter: position = rowptr[dst] + rank (from hist pass) ----
__global__ __launch_bounds__(256) void k_scatter(
    const int* __restrict__ esrc, const int* __restrict__ edst,
    const int* __restrict__ rowptr, const int* __restrict__ rank,
    int* __restrict__ csrc, int e)
{
  for (int i = blockIdx.x * 256 + threadIdx.x; i < e; i += gridDim.x * 256)
    csrc[rowptr[edst[i]] + rank[i]] = esrc[i] << 9;   // byte offset into KVb
}

// ---------------- fused QKVS projection GEMM (bf16 MFMA, 64-row tile, 4 phases) --------
// outputs: Q (f16, pre-scaled by log2e/sqrt(32)), KV interleaved (f16), S (f16)
template<int ABF16>
__global__ __launch_bounds__(256, 3) void k_qkvs(
    const void* __restrict__ Ain, const unsigned short* __restrict__ Wl,
    const float* __restrict__ Bl, unsigned short* __restrict__ Qb,
    unsigned short* __restrict__ KVb, unsigned short* __restrict__ Sb, int n)
{
  __shared__ unsigned short sA[64 * 128];    // 16 KB
  __shared__ unsigned short sW[128 * 128];   // 32 KB
  const int tid = threadIdx.x;
  const int rb = blockIdx.x * 64;
  const float QSC = 0.25503487f;   // (1/sqrt(32)) * log2(e)

  if (ABF16) {
    const unsigned short* A = (const unsigned short*)Ain;
    #pragma unroll
    for (int it = 0; it < 4; ++it) {
      int q = tid + it * 256;
      int row = q >> 4, ch = q & 15;
      int gr = rb + row;
      short8 h = {0,0,0,0,0,0,0,0};
      if (gr < n) h = *reinterpret_cast<const short8*>(A + (size_t)gr * HID + ch * 8);
      *reinterpret_cast<short8*>(&sA[row * 128 + ((ch ^ (row & 7)) << 3)]) = h;
    }
  } else {
    const float* A = (const float*)Ain;
    #pragma unroll
    for (int it = 0; it < 8; ++it) {
      int q = tid + it * 256;
      int row = q >> 5, c4 = (q & 31) * 4;
      int gr = rb + row;
      f32x4 a = {0.f, 0.f, 0.f, 0.f};
      if (gr < n) a = *reinterpret_cast<const f32x4*>(A + (size_t)gr * HID + c4);
      short4v h;
      h.x = (short)f2bf(a.x); h.y = (short)f2bf(a.y);
      h.z = (short)f2bf(a.z); h.w = (short)f2bf(a.w);
      int eloff = row * 128 + (((c4 >> 3) ^ (row & 7)) << 3) + (c4 & 7);
      *reinterpret_cast<short4v*>(&sA[eloff]) = h;
    }
  }

  const int lane = tid & 63;
  const int wv = tid >> 6;

  auto stageW = [&](int y) {
    const unsigned short* Wy = Wl + (size_t)y * 16384;
    #pragma unroll
    for (int it = 0; it < 8; ++it) {
      int q = tid + it * 256;
      int c = q >> 4, ch = q & 15;
      short8 w = *reinterpret_cast<const short8*>(Wy + c * 128 + ch * 8);
      *reinterpret_cast<short8*>(&sW[c * 128 + ((ch ^ (c & 7)) << 3)]) = w;
    }
  };

  stageW(0);
  __syncthreads();

  short8 af[4];
  #pragma unroll
  for (int ks = 0; ks < 4; ++ks) {
    int ch = ks * 4 + (lane >> 4);
    int row = wv * 16 + (lane & 15);
    af[ks] = *reinterpret_cast<const short8*>(&sA[row * 128 + ((ch ^ (row & 7)) << 3)]);
  }

  f32x4 acc[8];
  auto compute = [&]() {
    #pragma unroll
    for (int mf = 0; mf < 8; ++mf) acc[mf] = (f32x4){0.f, 0.f, 0.f, 0.f};
    #pragma unroll
    for (int ks = 0; ks < 4; ++ks) {
      int ch = ks * 4 + (lane >> 4);
      short8 wf[8];
      #pragma unroll
      for (int mf = 0; mf < 8; ++mf) {
        int wc = mf * 16 + (lane & 15);
        wf[mf] = *reinterpret_cast<const short8*>(&sW[wc * 128 + ((ch ^ (wc & 7)) << 3)]);
      }
      #pragma unroll
      for (int mf = 0; mf < 8; ++mf)
        acc[mf] = __builtin_amdgcn_mfma_f32_16x16x32_bf16(wf[mf], af[ks], acc[mf], 0, 0, 0);
    }
  };

  const int gr = rb + wv * 16 + (lane & 15);
  const int cbase = (lane >> 4) << 2;

  // ---- phase 0: Q (f16, pre-scaled) ----
  compute();
  if (gr < n) {
    #pragma unroll
    for (int mf = 0; mf < 8; ++mf) {
      int c0 = mf * 16 + cbase;
      f32x4 b = *reinterpret_cast<const f32x4*>(Bl + 0 * 128 + c0);
      f32x4 v = acc[mf];
      ushort4v h;
      h.x = f2h((v.x + b.x) * QSC); h.y = f2h((v.y + b.y) * QSC);
      h.z = f2h((v.z + b.z) * QSC); h.w = f2h((v.w + b.w) * QSC);
      *reinterpret_cast<ushort4v*>(Qb + (size_t)gr * HID + c0) = h;
    }
  }

  // ---- phase 1: S (f16) ----
  __syncthreads();
  stageW(3);
  __syncthreads();
  compute();
  if (gr < n) {
    #pragma unroll
    for (int mf = 0; mf < 8; ++mf) {
      int c0 = mf * 16 + cbase;
      f32x4 b = *reinterpret_cast<const f32x4*>(Bl + 3 * 128 + c0);
      f32x4 v = acc[mf];
      ushort4v h;
      h.x = f2h(v.x + b.x); h.y = f2h(v.y + b.y);
      h.z = f2h(v.z + b.z); h.w = f2h(v.w + b.w);
      *reinterpret_cast<ushort4v*>(Sb + (size_t)gr * HID + c0) = h;
    }
  }

  // ---- phase 2: K (held in registers) ----
  __syncthreads();
  stageW(1);
  __syncthreads();
  compute();
  f32x4 kacc[8];
  #pragma unroll
  for (int mf = 0; mf < 8; ++mf) kacc[mf] = acc[mf];

  // ---- phase 3: V, store interleaved KV (f16) ----
  __syncthreads();
  stageW(2);
  __syncthreads();
  compute();
  if (gr < n) {
    #pragma unroll
    for (int mf = 0; mf < 8; ++mf) {
      int c0 = mf * 16 + cbase;
      f32x4 bk = *reinterpret_cast<const f32x4*>(Bl + 1 * 128 + c0);
      f32x4 bv = *reinterpret_cast<const f32x4*>(Bl + 2 * 128 + c0);
      f32x4 kv = kacc[mf], vv = acc[mf];
      short8 h;
      h[0] = (short)f2h(kv.x + bk.x); h[1] = (short)f2h(kv.y + bk.y);
      h[2] = (short)f2h(vv.x + bv.x); h[3] = (short)f2h(vv.y + bv.y);
      h[4] = (short)f2h(kv.z + bk.z); h[5] = (short)f2h(kv.w + bk.w);
      h[6] = (short)f2h(vv.z + bv.z); h[7] = (short)f2h(vv.w + bv.w);
      *reinterpret_cast<short8*>(KVb + (size_t)gr * 256 + 2 * c0) = h;
    }
  }
}

// ---------------- fused attention + skip + relu (f16, v_dot2, deferred rescale) --------
__global__ __launch_bounds__(256, 8) void k_attn2(
    const unsigned short* __restrict__ Qb, const unsigned short* __restrict__ KVb,
    const unsigned short* __restrict__ Sb, const int* __restrict__ rowptr,
    const int* __restrict__ csrc, unsigned short* __restrict__ Hout, int n)
{
  int wid = blockIdx.x * 4 + (threadIdx.x >> 6);
  if (wid >= n) return;
  int lane = threadIdx.x & 63;
  half2v qh = b2h2(*reinterpret_cast<const unsigned*>(Qb + (size_t)wid * HID + 2 * lane));
  int e0 = rowptr[wid], deg = rowptr[wid + 1] - e0;
  const int* cp = csrc + e0;
  const char* kvb = (const char*)KVb + lane * 8;
  float m = -INFINITY, s = 0.f, a0 = 0.f, a1 = 0.f;

  auto LDo = [&](int off) -> uint2v {
    return *reinterpret_cast<const uint2v*>(kvb + (unsigned)off);
  };
  auto proc1 = [&](uint2v kv) {
    float lg = dpp_rsum16(__builtin_amdgcn_fdot2(qh, b2h2(kv.x), 0.f, false));
    if (!__all(lg <= m + 11.5f)) {
      float nm = fmaxf(m, lg);
      float cc = __builtin_amdgcn_exp2f(m - nm);
      s *= cc; a0 *= cc; a1 *= cc; m = nm;
    }
    float p = __builtin_amdgcn_exp2f(lg - m);
    half2v vh = b2h2(kv.y);
    s += p;
    a0 = fmaf(p, (float)vh.x, a0);
    a1 = fmaf(p, (float)vh.y, a1);
  };
  auto proc4 = [&](uint2v e0v, uint2v e1v, uint2v e2v, uint2v e3v) {
    float l0 = dpp_rsum16(__builtin_amdgcn_fdot2(qh, b2h2(e0v.x), 0.f, false));
    float l1 = dpp_rsum16(__builtin_amdgcn_fdot2(qh, b2h2(e1v.x), 0.f, false));
    float l2 = dpp_rsum16(__builtin_amdgcn_fdot2(qh, b2h2(e2v.x), 0.f, false));
    float l3 = dpp_rsum16(__builtin_amdgcn_fdot2(qh, b2h2(e3v.x), 0.f, false));
    float qm = fmaxf(fmaxf(l0, l1), fmaxf(l2, l3));
    if (!__all(qm <= m + 11.5f)) {       // rare, wave-uniform
      float nm = fmaxf(m, qm);
      float cc = __builtin_amdgcn_exp2f(m - nm);
      s *= cc; a0 *= cc; a1 *= cc; m = nm;
    }
    float p0 = __builtin_amdgcn_exp2f(l0 - m);
    float p1 = __builtin_amdgcn_exp2f(l1 - m);
    float p2 = __builtin_amdgcn_exp2f(l2 - m);
    float p3 = __builtin_amdgcn_exp2f(l3 - m);
    s += (p0 + p1) + (p2 + p3);
    half2v v0 = b2h2(e0v.y), v1 = b2h2(e1v.y), v2 = b2h2(e2v.y), v3 = b2h2(e3v.y);
    a0 = fmaf(p3, (float)v3.x, fmaf(p2, (float)v2.x, fmaf(p1, (float)v1.x, fmaf(p0, (float)v0.x, a0))));
    a1 = fmaf(p3, (float)v3.y, fmaf(p2, (float)v2.y, fmaf(p1, (float)v1.y, fmaf(p0, (float)v0.y, a1))));
  };

  int nq = deg >> 2, r = deg & 3;
  if (nq) {
    int4v o; __builtin_memcpy(&o, cp, 16);
    uint2v b0 = LDo(o.x), b1 = LDo(o.y), b2 = LDo(o.z), b3 = LDo(o.w);
    for (int q = 1; q < nq; ++q) {
      int4v no; __builtin_memcpy(&no, cp + 4 * q, 16);
      uint2v n0 = LDo(no.x), n1 = LDo(no.y), n2 = LDo(no.z), n3 = LDo(no.w);
      proc4(b0, b1, b2, b3);
      b0 = n0; b1 = n1; b2 = n2; b3 = n3;
    }
    proc4(b0, b1, b2, b3);
  }
  int tb = nq * 4;
  for (int i = 0; i < r; ++i) proc1(LDo(cp[tb + i]));

  float inv = (s > 0.f) ? 1.f / s : 0.f;
  half2v sh = b2h2(*reinterpret_cast<const unsigned*>(Sb + (size_t)wid * HID + 2 * lane));
  ushort2v h;
  h.x = f2bf(fmaxf(fmaf(a0, inv, (float)sh.x), 0.f));
  h.y = f2bf(fmaxf(fmaf(a1, inv, (float)sh.y), 0.f));
  *reinterpret_cast<ushort2v*>(Hout + (size_t)wid * HID + 2 * lane) = h;
}

// ---------------- fused mean-pool + FC (64 blocks, one per group; zero atomics) --------
__global__ __launch_bounds__(256) void k_poolfc(
    const unsigned short* __restrict__ H, const int* __restrict__ batch,
    const float* __restrict__ Wfc, const float* __restrict__ bfc,
    float* __restrict__ out, int n)
{
  int g = blockIdx.x;
  int lo = 0, hi = n;
  while (lo < hi) { int mid = (lo + hi) >> 1; if (batch[mid] < g) lo = mid + 1; else hi = mid; }
  int start = lo;
  hi = n;
  while (lo < hi) { int mid = (lo + hi) >> 1; if (batch[mid] < g + 1) lo = mid + 1; else hi = mid; }
  int end = lo;

  int t = threadIdx.x;
  int col = t & 127, rr = t >> 7;        // 2 row-streams x 128 cols
  float a0 = 0.f, a1 = 0.f, a2 = 0.f, a3 = 0.f;
  int i = start + rr;
  for (; i + 6 < end; i += 8) {
    a0 += bf2f(H[(size_t)i * HID + col]);
    a1 += bf2f(H[(size_t)(i + 2) * HID + col]);
    a2 += bf2f(H[(size_t)(i + 4) * HID + col]);
    a3 += bf2f(H[(size_t)(i + 6) * HID + col]);
  }
  for (; i < end; i += 2) a0 += bf2f(H[(size_t)i * HID + col]);
  float v = ((a0 + a1) + (a2 + a3)) * Wfc[col];

  __shared__ float red[4];
  #pragma unroll
  for (int off = 32; off >= 1; off >>= 1) v += __shfl_xor(v, off);
  if ((t & 63) == 0) red[t >> 6] = v;
  __syncthreads();
  if (t == 0) {
    float tot = (red[0] + red[1]) + (red[2] + red[3]);
    float cnt = (float)(end - start);
    out[g] = tot / fmaxf(cnt, 1.f) + bfc[0];
  }
}

extern "C" void kernel_launch(void* const* d_in, const int* in_sizes, int n_in,
                              void* d_out, int out_size, void* d_ws, size_t ws_size,
                              hipStream_t stream)
{
  const float* x   = (const float*)d_in[0];
  const int*   ei  = (const int*)d_in[1];
  const int*   bat = (const int*)d_in[2];
  const float *Wq1 = (const float*)d_in[3],  *bq1 = (const float*)d_in[4];
  const float *Wk1 = (const float*)d_in[5],  *bk1 = (const float*)d_in[6];
  const float *Wv1 = (const float*)d_in[7],  *bv1 = (const float*)d_in[8];
  const float *Ws1 = (const float*)d_in[9],  *bs1 = (const float*)d_in[10];
  const float *Wq2 = (const float*)d_in[11], *bq2 = (const float*)d_in[12];
  const float *Wk2 = (const float*)d_in[13], *bk2 = (const float*)d_in[14];
  const float *Wv2 = (const float*)d_in[15], *bv2 = (const float*)d_in[16];
  const float *Ws2 = (const float*)d_in[17], *bs2 = (const float*)d_in[18];
  const float *Wfc = (const float*)d_in[19], *bfc = (const float*)d_in[20];
  float* out = (float*)d_out;

  const int N = in_sizes[0] / HID;
  const int E = in_sizes[1] / 2;
  const int G = 64;

  char* p = (char*)d_ws;
  auto alloc = [&](size_t bytes) -> char* { char* r = p; p += align256(bytes); return r; };
  unsigned short* Qb  = (unsigned short*)alloc((size_t)N * HID * 2);   // f16
  unsigned short* KVb = (unsigned short*)alloc((size_t)N * 256 * 2);   // f16 interleaved
  unsigned short* Sb  = (unsigned short*)alloc((size_t)N * HID * 2);   // f16
  unsigned short* Hb  = (unsigned short*)alloc((size_t)N * HID * 2);   // bf16
  unsigned short* H2b = (unsigned short*)alloc((size_t)N * HID * 2);   // bf16
  unsigned short* Wcat = (unsigned short*)alloc((size_t)8 * 128 * 128 * 2);
  float* Bcat = (float*)alloc((size_t)8 * 128 * 4);
  int* rowptr = (int*)alloc((size_t)(N + 1) * sizeof(int));
  int* deg    = (int*)alloc((size_t)N * sizeof(int));
  int* rank   = (int*)alloc((size_t)E * sizeof(int));
  int* bsum   = (int*)alloc(4096);
  int* csrc   = (int*)alloc((size_t)E * sizeof(int));

  const int* esrc = ei;
  const int* edst = ei + E;

  hipMemsetAsync(deg, 0, (size_t)N * sizeof(int), stream);

  // wprep (blocks 0-127) || hist+rank (blocks 128-639)
  k_prep<<<640, 512, 0, stream>>>(
      Wq1, Wk1, Wv1, Ws1, Wq2, Wk2, Wv2, Ws2,
      bq1, bk1, bv1, bs1, bq2, bk2, bv2, bs2,
      Wcat, Bcat, edst, deg, rank, E);

  int SB = (N + 511) / 512;
  k_scan_a<<<SB, 512, 0, stream>>>(deg, rowptr, bsum, N);
  k_scan_c<<<SB, 512, 0, stream>>>(rowptr, bsum, N, E, SB);
  k_scatter<<<512, 256, 0, stream>>>(esrc, edst, rowptr, rank, csrc, E);

  int QB = (N + 63) / 64;
  // layer 1 (fp32 input)
  k_qkvs<0><<<QB, 256, 0, stream>>>(x, Wcat, Bcat, Qb, KVb, Sb, N);
  k_attn2<<<(N + 3) / 4, 256, 0, stream>>>(Qb, KVb, Sb, rowptr, csrc, Hb, N);
  // layer 2 (bf16 input)
  k_qkvs<1><<<QB, 256, 0, stream>>>(Hb, Wcat + 4 * 16384, Bcat + 512, Qb, KVb, Sb, N);
  k_attn2<<<(N + 3) / 4, 256, 0, stream>>>(Qb, KVb, Sb, rowptr, csrc, H2b, N);
  // mean-pool + fc
  k_poolfc<<<G, 256, 0, stream>>>(H2b, bat, Wfc, bfc, out, N);
}